// Round 4
// baseline (1403.527 us; speedup 1.0000x reference)
//
#include <hip/hip_runtime.h>
#include <math.h>

#define H_HERBS 25000
#define DIM 128
#define G_HERBS 16          // herbs per block in k_seg_attn
#define SCAP 1024           // score buffer rows per block (avg ~320, 1024 = +39 sigma)

// ---------------- K1: segment starts via binary search (indices sorted) ---
__global__ void k_starts(const int* __restrict__ idxA, const int* __restrict__ idxB,
                         int nA, int nB, int* __restrict__ startA, int* __restrict__ startB) {
    int h = blockIdx.x * blockDim.x + threadIdx.x;
    if (h > H_HERBS) return;
    {
        int lo = 0, hi = nA;
        while (lo < hi) { int mid = (lo + hi) >> 1; if (idxA[mid] < h) lo = mid + 1; else hi = mid; }
        startA[h] = lo;
    }
    {
        int lo = 0, hi = nB;
        while (lo < hi) { int mid = (lo + hi) >> 1; if (idxB[mid] < h) lo = mid + 1; else hi = mid; }
        startB[h] = lo;
    }
}

// ---------------- K2: per-herb mean projected through aw1[128:256,:] + ab1
__global__ __launch_bounds__(64) void k_mean_both(
        const float* __restrict__ hA, const float* __restrict__ hB,
        const int* __restrict__ startA, const int* __restrict__ startB,
        const float* __restrict__ aw1, const float* __restrict__ ab1,
        float* __restrict__ mpartA, float* __restrict__ mpartB) {
    int bid = blockIdx.x;
    bool sideA = bid < H_HERBS;              // sideA -> reads B rows
    int h = sideA ? bid : bid - H_HERBS;
    const float* X = sideA ? hB : hA;
    const int* start = sideA ? startB : startA;
    float* mpart = sideA ? mpartA : mpartB;

    int lane = threadIdx.x;
    int half = lane >> 5, li = lane & 31;    // 64 lanes = 2 rows x 32 float4
    int s = start[h], e = start[h + 1];
    const float4* X4 = (const float4*)X;
    float4 acc = make_float4(0.f, 0.f, 0.f, 0.f);
    for (int r = s + half; r < e; r += 2) {
        float4 v = X4[(size_t)r * 32 + li];
        acc.x += v.x; acc.y += v.y; acc.z += v.z; acc.w += v.w;
    }
    acc.x += __shfl_xor(acc.x, 32, 64);
    acc.y += __shfl_xor(acc.y, 32, 64);
    acc.z += __shfl_xor(acc.z, 32, 64);
    acc.w += __shfl_xor(acc.w, 32, 64);

    int cnt = e - s;
    float inv = 1.0f / (float)(cnt > 1 ? cnt : 1);
    __shared__ float mean[DIM];
    if (half == 0) {
        mean[4 * li]     = acc.x * inv;
        mean[4 * li + 1] = acc.y * inv;
        mean[4 * li + 2] = acc.z * inv;
        mean[4 * li + 3] = acc.w * inv;
    }
    __syncthreads();
    int j = lane;
    float m = ab1[j];
    #pragma unroll 8
    for (int k = 0; k < 128; ++k) {
        m += mean[k] * aw1[(size_t)(128 + k) * 64 + j];
    }
    mpart[(size_t)h * 64 + j] = m;
}

// ---------------- K3: fused scores + per-herb softmax + weighted sum ------
// Block = 16 consecutive herbs (contiguous row range). Phase A: scores for
// 64-row chunks (thread = 4 rows x 16 j, W in LDS, double-buffered X loads)
// -> LDS. Phase B: per-herb exact softmax + weighted accumulate (X from L2).
__global__ __launch_bounds__(256) void k_seg_attn(
        const float* __restrict__ XA, const int* __restrict__ idxA,
        const int* __restrict__ startA, const float* __restrict__ mpartA,
        const float* __restrict__ XB, const int* __restrict__ idxB,
        const int* __restrict__ startB, const float* __restrict__ mpartB,
        const float* __restrict__ aw1, const float* __restrict__ aw2,
        const float* __restrict__ ab2, int nblk,
        float* __restrict__ outA, float* __restrict__ outB) {
    bool isA = (int)blockIdx.x < nblk;
    int blk = isA ? blockIdx.x : blockIdx.x - nblk;
    const float* X = isA ? XA : XB;
    const int* idx = isA ? idxA : idxB;
    const int* start = isA ? startA : startB;
    const float* mpart = isA ? mpartA : mpartB;
    float* out = isA ? outA : outB;

    __shared__ float4 Wl[128 * 16];   // 32 KB: aw1[0:128,:]
    __shared__ float sc[SCAP];        // 4 KB: scores -> p
    __shared__ float red[256];        // 1 KB

    int t = threadIdx.x;
    const float4* W4 = (const float4*)aw1;
    #pragma unroll
    for (int q = 0; q < 8; ++q) Wl[t + 256 * q] = W4[t + 256 * q];
    __syncthreads();

    int h0 = blk * G_HERBS;
    int hEnd = h0 + G_HERBS; if (hEnd > H_HERBS) hEnd = H_HERBS;
    int rs = start[h0];
    int re = start[hEnd];
    int cntb = re - rs; if (cntb > SCAP) cntb = SCAP;

    int rl = t >> 2, jq = t & 3;          // 16 rl x 4 jq; 4 rows per thread
    // per-thread aw2 slice (16 j) in registers
    float4 a2r[4];
    {
        const float4* A24 = ((const float4*)aw2) + jq * 4;
        #pragma unroll
        for (int q = 0; q < 4; ++q) a2r[q] = A24[q];
    }
    float b2s = ab2[0];

    // ---------------- phase A: scores for all rows of the block ----------
    for (int c0 = 0; c0 < cntb; c0 += 64) {
        int lr[4]; bool vm[4];
        const float4* Xp[4];
        #pragma unroll
        for (int m = 0; m < 4; ++m) {
            lr[m] = c0 + rl + 16 * m;
            vm[m] = lr[m] < cntb;
            Xp[m] = (const float4*)(X + (size_t)(rs + (vm[m] ? lr[m] : 0)) * DIM);
        }

        float4 acc[4][4];
        #pragma unroll
        for (int m = 0; m < 4; ++m)
            #pragma unroll
            for (int q = 0; q < 4; ++q) acc[m][q] = make_float4(0.f, 0.f, 0.f, 0.f);

        float4 xa[4], xb[4];
        #pragma unroll
        for (int m = 0; m < 4; ++m) xa[m] = Xp[m][0];

#define SCORE_STEP(XV, KQ)                                                   \
        {                                                                    \
            _Pragma("unroll")                                                \
            for (int kk = 0; kk < 4; ++kk) {                                 \
                int k = (KQ) * 4 + kk;                                       \
                float4 w[4];                                                 \
                _Pragma("unroll")                                            \
                for (int q = 0; q < 4; ++q) w[q] = Wl[k * 16 + jq * 4 + q];  \
                _Pragma("unroll")                                            \
                for (int m = 0; m < 4; ++m) {                                \
                    float x = (&XV[m].x)[kk];                                \
                    _Pragma("unroll")                                        \
                    for (int q = 0; q < 4; ++q) {                            \
                        acc[m][q].x += x * w[q].x; acc[m][q].y += x * w[q].y;\
                        acc[m][q].z += x * w[q].z; acc[m][q].w += x * w[q].w;\
                    }                                                        \
                }                                                            \
            }                                                                \
        }

        for (int kq = 0; kq < 32; kq += 2) {
            #pragma unroll
            for (int m = 0; m < 4; ++m) xb[m] = Xp[m][kq + 1];
            SCORE_STEP(xa, kq)
            if (kq + 2 < 32) {
                #pragma unroll
                for (int m = 0; m < 4; ++m) xa[m] = Xp[m][kq + 2];
            }
            SCORE_STEP(xb, kq + 1)
        }
#undef SCORE_STEP

        #pragma unroll
        for (int m = 0; m < 4; ++m) {
            float s = 0.f;
            int h = vm[m] ? idx[rs + lr[m]] : h0;
            const float4* mp = (const float4*)(mpart + (size_t)h * 64) + jq * 4;
            #pragma unroll
            for (int q = 0; q < 4; ++q) {
                float4 mv = mp[q];
                float hx = acc[m][q].x + mv.x, hy = acc[m][q].y + mv.y;
                float hz = acc[m][q].z + mv.z, hw = acc[m][q].w + mv.w;
                hx = hx > 0.f ? hx : 0.2f * hx; hy = hy > 0.f ? hy : 0.2f * hy;
                hz = hz > 0.f ? hz : 0.2f * hz; hw = hw > 0.f ? hw : 0.2f * hw;
                s += hx * a2r[q].x + hy * a2r[q].y + hz * a2r[q].z + hw * a2r[q].w;
            }
            s += __shfl_xor(s, 1, 64);
            s += __shfl_xor(s, 2, 64);
            if (jq == 0 && vm[m]) sc[lr[m]] = s + b2s;
        }
    }
    __syncthreads();

    // ---------------- phase B: per-herb softmax + weighted accumulate -----
    for (int hh = 0; hh < G_HERBS; ++hh) {
        int h = h0 + hh;
        if (h >= H_HERBS) break;
        int ls = start[h] - rs;
        int le = start[h + 1] - rs;
        if (ls > cntb) ls = cntb;
        if (le > cntb) le = cntb;
        int cnt = le - ls;

        if (t < 64 && cnt > 0) {
            float mx = -INFINITY;
            for (int r = ls + t; r < le; r += 64) mx = fmaxf(mx, sc[r]);
            #pragma unroll
            for (int o = 32; o; o >>= 1) mx = fmaxf(mx, __shfl_xor(mx, o, 64));
            float sum = 0.f;
            for (int r = ls + t; r < le; r += 64) {
                float e = __expf(sc[r] - mx);
                sc[r] = e;
                sum += e;
            }
            #pragma unroll
            for (int o = 32; o; o >>= 1) sum += __shfl_xor(sum, o, 64);
            float invden = 1.0f / (sum + 1e-16f);
            for (int r = ls + t; r < le; r += 64) sc[r] *= invden;
        }
        __syncthreads();

        int c = t & 127, g = t >> 7;
        float O = 0.f;
        for (int r = ls + g; r < le; r += 2)
            O += sc[r] * X[(size_t)(rs + r) * DIM + c];
        red[t] = O;
        __syncthreads();
        if (t < 128) out[(size_t)h * DIM + t] = red[t] + red[128 + t];
        __syncthreads();
    }
}

// ---------------- K4: fusion MLP, register-tiled GEMM -----------------
#define HPB 16
__global__ __launch_bounds__(256) void k_fusion(
        const float* __restrict__ HA, const float* __restrict__ HB,
        const float* __restrict__ fw1, const float* __restrict__ fb1,
        const float* __restrict__ fw2, const float* __restrict__ fb2,
        float* __restrict__ out) {
    __shared__ float feat[HPB][512];
    __shared__ float hid[HPB][256];
    int t = threadIdx.x;
    int h0 = blockIdx.x * HPB;

    for (int idx = t; idx < HPB * DIM; idx += 256) {
        int hh = idx >> 7, c = idx & 127;
        int h = h0 + hh;
        float a = 0.f, b = 0.f;
        if (h < H_HERBS) { a = HA[(size_t)h * DIM + c]; b = HB[(size_t)h * DIM + c]; }
        feat[hh][c]       = a;
        feat[hh][128 + c] = b;
        feat[hh][256 + c] = a * b;
        feat[hh][384 + c] = fabsf(a - b);
    }
    __syncthreads();

    {
        int c = t & 63, g = t >> 6;
        float4 acc[4];
        #pragma unroll
        for (int m = 0; m < 4; ++m) acc[m] = make_float4(0.f, 0.f, 0.f, 0.f);
        const float4* W1 = (const float4*)fw1;
        for (int k = 0; k < 512; k += 4) {
            float4 w0 = W1[(size_t)(k + 0) * 64 + c];
            float4 w1 = W1[(size_t)(k + 1) * 64 + c];
            float4 w2 = W1[(size_t)(k + 2) * 64 + c];
            float4 w3 = W1[(size_t)(k + 3) * 64 + c];
            #pragma unroll
            for (int m = 0; m < 4; ++m) {
                float4 f = *(const float4*)&feat[4 * g + m][k];
                acc[m].x += f.x * w0.x + f.y * w1.x + f.z * w2.x + f.w * w3.x;
                acc[m].y += f.x * w0.y + f.y * w1.y + f.z * w2.y + f.w * w3.y;
                acc[m].z += f.x * w0.z + f.y * w1.z + f.z * w2.z + f.w * w3.z;
                acc[m].w += f.x * w0.w + f.y * w1.w + f.z * w2.w + f.w * w3.w;
            }
        }
        float4 b1v = ((const float4*)fb1)[c];
        #pragma unroll
        for (int m = 0; m < 4; ++m) {
            float4 hv;
            hv.x = fmaxf(acc[m].x + b1v.x, 0.f);
            hv.y = fmaxf(acc[m].y + b1v.y, 0.f);
            hv.z = fmaxf(acc[m].z + b1v.z, 0.f);
            hv.w = fmaxf(acc[m].w + b1v.w, 0.f);
            *(float4*)&hid[4 * g + m][4 * c] = hv;
        }
    }
    __syncthreads();

    {
        int c2 = t & 31, g2 = t >> 5;
        float4 acc[2];
        #pragma unroll
        for (int m = 0; m < 2; ++m) acc[m] = make_float4(0.f, 0.f, 0.f, 0.f);
        const float4* W2 = (const float4*)fw2;
        for (int k = 0; k < 256; k += 4) {
            float4 w0 = W2[(size_t)(k + 0) * 32 + c2];
            float4 w1 = W2[(size_t)(k + 1) * 32 + c2];
            float4 w2v = W2[(size_t)(k + 2) * 32 + c2];
            float4 w3 = W2[(size_t)(k + 3) * 32 + c2];
            #pragma unroll
            for (int m = 0; m < 2; ++m) {
                float4 hv = *(const float4*)&hid[2 * g2 + m][k];
                acc[m].x += hv.x * w0.x + hv.y * w1.x + hv.z * w2v.x + hv.w * w3.x;
                acc[m].y += hv.x * w0.y + hv.y * w1.y + hv.z * w2v.y + hv.w * w3.y;
                acc[m].z += hv.x * w0.z + hv.y * w1.z + hv.z * w2v.z + hv.w * w3.z;
                acc[m].w += hv.x * w0.w + hv.y * w1.w + hv.z * w2v.w + hv.w * w3.w;
            }
        }
        float4 b2v = ((const float4*)fb2)[c2];
        #pragma unroll
        for (int m = 0; m < 2; ++m) {
            int h = h0 + 2 * g2 + m;
            if (h < H_HERBS) {
                float4 o;
                o.x = acc[m].x + b2v.x; o.y = acc[m].y + b2v.y;
                o.z = acc[m].z + b2v.z; o.w = acc[m].w + b2v.w;
                ((float4*)out)[(size_t)h * 32 + c2] = o;
            }
        }
    }
}

extern "C" void kernel_launch(void* const* d_in, const int* in_sizes, int n_in,
                              void* d_out, int out_size, void* d_ws, size_t ws_size,
                              hipStream_t stream) {
    const float* hA  = (const float*)d_in[0];
    const float* hB  = (const float*)d_in[1];
    const int*   idxA = (const int*)d_in[2];
    const int*   idxB = (const int*)d_in[3];
    const float* aw1 = (const float*)d_in[5];
    const float* ab1 = (const float*)d_in[6];
    const float* aw2 = (const float*)d_in[7];
    const float* ab2 = (const float*)d_in[8];
    const float* fw1 = (const float*)d_in[9];
    const float* fb1 = (const float*)d_in[10];
    const float* fw2 = (const float*)d_in[11];
    const float* fb2 = (const float*)d_in[12];

    int nA = in_sizes[0] / DIM;
    int nB = in_sizes[1] / DIM;

    float* out  = (float*)d_out;
    float* outI = out;
    float* outA = out + (size_t)H_HERBS * DIM;
    float* outB = out + (size_t)2 * H_HERBS * DIM;

    char* w = (char*)d_ws;
    auto carve = [&](size_t bytes) { char* p = w; w += (bytes + 255) & ~(size_t)255; return p; };
    int*   startA  = (int*)carve((size_t)(H_HERBS + 1) * sizeof(int));
    int*   startB  = (int*)carve((size_t)(H_HERBS + 1) * sizeof(int));
    float* mpartA  = (float*)carve((size_t)H_HERBS * 64 * sizeof(float));
    float* mpartB  = (float*)carve((size_t)H_HERBS * 64 * sizeof(float));

    k_starts<<<(H_HERBS + 1 + 255) / 256, 256, 0, stream>>>(idxA, idxB, nA, nB, startA, startB);

    k_mean_both<<<2 * H_HERBS, 64, 0, stream>>>(hA, hB, startA, startB, aw1, ab1, mpartA, mpartB);

    int nblk = (H_HERBS + G_HERBS - 1) / G_HERBS;
    k_seg_attn<<<2 * nblk, 256, 0, stream>>>(hA, idxA, startA, mpartA,
                                             hB, idxB, startB, mpartB,
                                             aw1, aw2, ab2, nblk, outA, outB);

    k_fusion<<<(H_HERBS + HPB - 1) / HPB, 256, 0, stream>>>(outA, outB, fw1, fb1, fw2, fb2, outI);
}

// Round 5
// 640.204 us; speedup vs baseline: 2.1923x; 2.1923x over previous
//
#include <hip/hip_runtime.h>
#include <math.h>

#define H_HERBS 25000
#define DIM 128

// ---------------- K1: segment starts via binary search (indices sorted) ---
__global__ void k_starts(const int* __restrict__ idxA, const int* __restrict__ idxB,
                         int nA, int nB, int* __restrict__ startA, int* __restrict__ startB) {
    int h = blockIdx.x * blockDim.x + threadIdx.x;
    if (h > H_HERBS) return;
    {
        int lo = 0, hi = nA;
        while (lo < hi) { int mid = (lo + hi) >> 1; if (idxA[mid] < h) lo = mid + 1; else hi = mid; }
        startA[h] = lo;
    }
    {
        int lo = 0, hi = nB;
        while (lo < hi) { int mid = (lo + hi) >> 1; if (idxB[mid] < h) lo = mid + 1; else hi = mid; }
        startB[h] = lo;
    }
}

// ---------------- K2: per-herb mean projected through aw1[128:256,:] + ab1
// float4 loads, 2 rows in parallel (32 lanes each), unroll 2 -> 4 loads in flight
__global__ __launch_bounds__(64) void k_mean_both(
        const float* __restrict__ hA, const float* __restrict__ hB,
        const int* __restrict__ startA, const int* __restrict__ startB,
        const float* __restrict__ aw1, const float* __restrict__ ab1,
        float* __restrict__ mpartA, float* __restrict__ mpartB) {
    int bid = blockIdx.x;
    bool sideA = bid < H_HERBS;              // sideA -> reads B rows
    int h = sideA ? bid : bid - H_HERBS;
    const float* X = sideA ? hB : hA;
    const int* start = sideA ? startB : startA;
    float* mpart = sideA ? mpartA : mpartB;

    int lane = threadIdx.x;
    int half = lane >> 5, li = lane & 31;
    int s = start[h], e = start[h + 1];
    const float4* X4 = (const float4*)X;
    float4 acc = make_float4(0.f, 0.f, 0.f, 0.f);
    int r = s + half;
    for (; r + 2 < e; r += 4) {
        float4 v0 = X4[(size_t)r * 32 + li];
        float4 v1 = X4[(size_t)(r + 2) * 32 + li];
        acc.x += v0.x + v1.x; acc.y += v0.y + v1.y;
        acc.z += v0.z + v1.z; acc.w += v0.w + v1.w;
    }
    if (r < e) {
        float4 v0 = X4[(size_t)r * 32 + li];
        acc.x += v0.x; acc.y += v0.y; acc.z += v0.z; acc.w += v0.w;
    }
    acc.x += __shfl_xor(acc.x, 32, 64);
    acc.y += __shfl_xor(acc.y, 32, 64);
    acc.z += __shfl_xor(acc.z, 32, 64);
    acc.w += __shfl_xor(acc.w, 32, 64);

    int cnt = e - s;
    float inv = 1.0f / (float)(cnt > 1 ? cnt : 1);
    __shared__ float mean[DIM];
    if (half == 0) {
        mean[4 * li]     = acc.x * inv;
        mean[4 * li + 1] = acc.y * inv;
        mean[4 * li + 2] = acc.z * inv;
        mean[4 * li + 3] = acc.w * inv;
    }
    __syncthreads();
    int j = lane;
    float m = ab1[j];
    #pragma unroll 8
    for (int k = 0; k < 128; ++k) {
        m += mean[k] * aw1[(size_t)(128 + k) * 64 + j];
    }
    mpart[(size_t)h * 64 + j] = m;
}

// ---------------- K3: attention scores, both sides --------------------
// Flat grid, block = 256 items. Thread = 4 consecutive items x 16 j (jq=t&3).
// Double-buffered X register prefetch.
__global__ __launch_bounds__(256) void k_scores_both(
        const float* __restrict__ XA, const int* __restrict__ idxA,
        const float* __restrict__ mpartA, int nA, int gridA,
        const float* __restrict__ XB, const int* __restrict__ idxB,
        const float* __restrict__ mpartB, int nB,
        const float* __restrict__ aw1, const float* __restrict__ aw2,
        const float* __restrict__ ab2,
        float* __restrict__ scoresA, float* __restrict__ scoresB) {
    bool isA = (int)blockIdx.x < gridA;
    int blk = isA ? blockIdx.x : blockIdx.x - gridA;
    const float* X = isA ? XA : XB;
    const int* idx = isA ? idxA : idxB;
    const float* mpart = isA ? mpartA : mpartB;
    float* scores = isA ? scoresA : scoresB;
    int n = isA ? nA : nB;

    __shared__ float4 Wl[128 * 16];    // aw1[0:128,:] as float4 (32 KB)
    __shared__ float4 A2l[16];

    int t = threadIdx.x;
    const float4* W4 = (const float4*)aw1;
    #pragma unroll
    for (int q = 0; q < 8; ++q) Wl[t + 256 * q] = W4[t + 256 * q];
    if (t < 16) A2l[t] = ((const float4*)aw2)[t];
    __syncthreads();

    int grp = t >> 2, jq = t & 3;            // 64 groups x 4 jq; 4 items each
    long base = (long)blk * 256 + grp * 4;

    const float4* Xp[4];
    bool valid[4];
    #pragma unroll
    for (int m = 0; m < 4; ++m) {
        valid[m] = (base + m) < n;
        Xp[m] = (const float4*)(X + (size_t)(valid[m] ? base + m : 0) * DIM);
    }

    float4 acc[4][4];
    #pragma unroll
    for (int m = 0; m < 4; ++m)
        #pragma unroll
        for (int q = 0; q < 4; ++q) acc[m][q] = make_float4(0.f, 0.f, 0.f, 0.f);

    const float4* Wbase = Wl + jq * 4;

    float4 xa[4], xb[4];
    #pragma unroll
    for (int m = 0; m < 4; ++m) xa[m] = Xp[m][0];

#define SCORE_STEP(XV, KQ)                                                   \
    {                                                                        \
        _Pragma("unroll")                                                    \
        for (int kk = 0; kk < 4; ++kk) {                                     \
            int k = (KQ) * 4 + kk;                                           \
            float4 w[4];                                                     \
            _Pragma("unroll")                                                \
            for (int q = 0; q < 4; ++q) w[q] = Wbase[k * 16 + q];            \
            _Pragma("unroll")                                                \
            for (int m = 0; m < 4; ++m) {                                    \
                float x = (&XV[m].x)[kk];                                    \
                _Pragma("unroll")                                            \
                for (int q = 0; q < 4; ++q) {                                \
                    acc[m][q].x += x * w[q].x; acc[m][q].y += x * w[q].y;    \
                    acc[m][q].z += x * w[q].z; acc[m][q].w += x * w[q].w;    \
                }                                                            \
            }                                                                \
        }                                                                    \
    }

    for (int kq = 0; kq < 32; kq += 2) {
        #pragma unroll
        for (int m = 0; m < 4; ++m) xb[m] = Xp[m][kq + 1];
        SCORE_STEP(xa, kq)
        if (kq + 2 < 32) {
            #pragma unroll
            for (int m = 0; m < 4; ++m) xa[m] = Xp[m][kq + 2];
        }
        SCORE_STEP(xb, kq + 1)
    }
#undef SCORE_STEP

    float b2s = ab2[0];
    #pragma unroll
    for (int m = 0; m < 4; ++m) {
        int h = valid[m] ? idx[base + m] : 0;
        const float4* mp = (const float4*)(mpart + (size_t)h * 64) + jq * 4;
        float s = 0.f;
        #pragma unroll
        for (int q = 0; q < 4; ++q) {
            float4 mv = mp[q], a2 = A2l[jq * 4 + q];
            float hx = acc[m][q].x + mv.x, hy = acc[m][q].y + mv.y;
            float hz = acc[m][q].z + mv.z, hw = acc[m][q].w + mv.w;
            hx = hx > 0.f ? hx : 0.2f * hx; hy = hy > 0.f ? hy : 0.2f * hy;
            hz = hz > 0.f ? hz : 0.2f * hz; hw = hw > 0.f ? hw : 0.2f * hw;
            s += hx * a2.x + hy * a2.y + hz * a2.z + hw * a2.w;
        }
        s += __shfl_xor(s, 1, 64);
        s += __shfl_xor(s, 2, 64);
        if (jq == 0 && valid[m]) scores[base + m] = s + b2s;
    }
}

// ---------------- K4: per-herb softmax + weighted row sum, both sides -----
// float4 loads, 2 rows x 32-lane halves, unroll 2.
__global__ __launch_bounds__(64) void k_attn_both(
        const float* __restrict__ hA, const float* __restrict__ hB,
        const int* __restrict__ startA, const int* __restrict__ startB,
        const float* __restrict__ scoresA, const float* __restrict__ scoresB,
        float* __restrict__ outA, float* __restrict__ outB) {
    int bid = blockIdx.x;
    bool sideA = bid < H_HERBS;
    int h = sideA ? bid : bid - H_HERBS;
    const float* X = sideA ? hA : hB;
    const int* start = sideA ? startA : startB;
    const float* scores = sideA ? scoresA : scoresB;
    float* out = sideA ? outA : outB;

    int lane = threadIdx.x;
    int half = lane >> 5, li = lane & 31;
    int s = start[h], e = start[h + 1];
    const float4* X4 = (const float4*)X;
    float4 acc = make_float4(0.f, 0.f, 0.f, 0.f);
    if (e > s) {
        float mx = -INFINITY;
        for (int r = s + lane; r < e; r += 64) mx = fmaxf(mx, scores[r]);
        #pragma unroll
        for (int o = 32; o; o >>= 1) mx = fmaxf(mx, __shfl_xor(mx, o, 64));
        float sum = 0.f;
        for (int r = s + lane; r < e; r += 64) sum += __expf(scores[r] - mx);
        #pragma unroll
        for (int o = 32; o; o >>= 1) sum += __shfl_xor(sum, o, 64);
        float invden = 1.0f / (sum + 1e-16f);

        int r = s + half;
        for (; r + 2 < e; r += 4) {
            float w0 = __expf(scores[r] - mx) * invden;
            float w1 = __expf(scores[r + 2] - mx) * invden;
            float4 v0 = X4[(size_t)r * 32 + li];
            float4 v1 = X4[(size_t)(r + 2) * 32 + li];
            acc.x += w0 * v0.x + w1 * v1.x;
            acc.y += w0 * v0.y + w1 * v1.y;
            acc.z += w0 * v0.z + w1 * v1.z;
            acc.w += w0 * v0.w + w1 * v1.w;
        }
        if (r < e) {
            float w0 = __expf(scores[r] - mx) * invden;
            float4 v0 = X4[(size_t)r * 32 + li];
            acc.x += w0 * v0.x; acc.y += w0 * v0.y;
            acc.z += w0 * v0.z; acc.w += w0 * v0.w;
        }
    }
    acc.x += __shfl_xor(acc.x, 32, 64);
    acc.y += __shfl_xor(acc.y, 32, 64);
    acc.z += __shfl_xor(acc.z, 32, 64);
    acc.w += __shfl_xor(acc.w, 32, 64);
    if (half == 0) {
        ((float4*)out)[(size_t)h * 32 + li] = acc;
    }
}

// ---------------- K5: fusion MLP, register-tiled GEMM -----------------
#define HPB 16
__global__ __launch_bounds__(256) void k_fusion(
        const float* __restrict__ HA, const float* __restrict__ HB,
        const float* __restrict__ fw1, const float* __restrict__ fb1,
        const float* __restrict__ fw2, const float* __restrict__ fb2,
        float* __restrict__ out) {
    __shared__ float feat[HPB][512];
    __shared__ float hid[HPB][256];
    int t = threadIdx.x;
    int h0 = blockIdx.x * HPB;

    for (int idx = t; idx < HPB * DIM; idx += 256) {
        int hh = idx >> 7, c = idx & 127;
        int h = h0 + hh;
        float a = 0.f, b = 0.f;
        if (h < H_HERBS) { a = HA[(size_t)h * DIM + c]; b = HB[(size_t)h * DIM + c]; }
        feat[hh][c]       = a;
        feat[hh][128 + c] = b;
        feat[hh][256 + c] = a * b;
        feat[hh][384 + c] = fabsf(a - b);
    }
    __syncthreads();

    {
        int c = t & 63, g = t >> 6;
        float4 acc[4];
        #pragma unroll
        for (int m = 0; m < 4; ++m) acc[m] = make_float4(0.f, 0.f, 0.f, 0.f);
        const float4* W1 = (const float4*)fw1;
        for (int k = 0; k < 512; k += 4) {
            float4 w0 = W1[(size_t)(k + 0) * 64 + c];
            float4 w1 = W1[(size_t)(k + 1) * 64 + c];
            float4 w2 = W1[(size_t)(k + 2) * 64 + c];
            float4 w3 = W1[(size_t)(k + 3) * 64 + c];
            #pragma unroll
            for (int m = 0; m < 4; ++m) {
                float4 f = *(const float4*)&feat[4 * g + m][k];
                acc[m].x += f.x * w0.x + f.y * w1.x + f.z * w2.x + f.w * w3.x;
                acc[m].y += f.x * w0.y + f.y * w1.y + f.z * w2.y + f.w * w3.y;
                acc[m].z += f.x * w0.z + f.y * w1.z + f.z * w2.z + f.w * w3.z;
                acc[m].w += f.x * w0.w + f.y * w1.w + f.z * w2.w + f.w * w3.w;
            }
        }
        float4 b1v = ((const float4*)fb1)[c];
        #pragma unroll
        for (int m = 0; m < 4; ++m) {
            float4 hv;
            hv.x = fmaxf(acc[m].x + b1v.x, 0.f);
            hv.y = fmaxf(acc[m].y + b1v.y, 0.f);
            hv.z = fmaxf(acc[m].z + b1v.z, 0.f);
            hv.w = fmaxf(acc[m].w + b1v.w, 0.f);
            *(float4*)&hid[4 * g + m][4 * c] = hv;
        }
    }
    __syncthreads();

    {
        int c2 = t & 31, g2 = t >> 5;
        float4 acc[2];
        #pragma unroll
        for (int m = 0; m < 2; ++m) acc[m] = make_float4(0.f, 0.f, 0.f, 0.f);
        const float4* W2 = (const float4*)fw2;
        for (int k = 0; k < 256; k += 4) {
            float4 w0 = W2[(size_t)(k + 0) * 32 + c2];
            float4 w1 = W2[(size_t)(k + 1) * 32 + c2];
            float4 w2v = W2[(size_t)(k + 2) * 32 + c2];
            float4 w3 = W2[(size_t)(k + 3) * 32 + c2];
            #pragma unroll
            for (int m = 0; m < 2; ++m) {
                float4 hv = *(const float4*)&hid[2 * g2 + m][k];
                acc[m].x += hv.x * w0.x + hv.y * w1.x + hv.z * w2v.x + hv.w * w3.x;
                acc[m].y += hv.x * w0.y + hv.y * w1.y + hv.z * w2v.y + hv.w * w3.y;
                acc[m].z += hv.x * w0.z + hv.y * w1.z + hv.z * w2v.z + hv.w * w3.z;
                acc[m].w += hv.x * w0.w + hv.y * w1.w + hv.z * w2v.w + hv.w * w3.w;
            }
        }
        float4 b2v = ((const float4*)fb2)[c2];
        #pragma unroll
        for (int m = 0; m < 2; ++m) {
            int h = h0 + 2 * g2 + m;
            if (h < H_HERBS) {
                float4 o;
                o.x = acc[m].x + b2v.x; o.y = acc[m].y + b2v.y;
                o.z = acc[m].z + b2v.z; o.w = acc[m].w + b2v.w;
                ((float4*)out)[(size_t)h * 32 + c2] = o;
            }
        }
    }
}

extern "C" void kernel_launch(void* const* d_in, const int* in_sizes, int n_in,
                              void* d_out, int out_size, void* d_ws, size_t ws_size,
                              hipStream_t stream) {
    const float* hA  = (const float*)d_in[0];
    const float* hB  = (const float*)d_in[1];
    const int*   idxA = (const int*)d_in[2];
    const int*   idxB = (const int*)d_in[3];
    const float* aw1 = (const float*)d_in[5];
    const float* ab1 = (const float*)d_in[6];
    const float* aw2 = (const float*)d_in[7];
    const float* ab2 = (const float*)d_in[8];
    const float* fw1 = (const float*)d_in[9];
    const float* fb1 = (const float*)d_in[10];
    const float* fw2 = (const float*)d_in[11];
    const float* fb2 = (const float*)d_in[12];

    int nA = in_sizes[0] / DIM;
    int nB = in_sizes[1] / DIM;

    float* out  = (float*)d_out;
    float* outI = out;
    float* outA = out + (size_t)H_HERBS * DIM;
    float* outB = out + (size_t)2 * H_HERBS * DIM;

    char* w = (char*)d_ws;
    auto carve = [&](size_t bytes) { char* p = w; w += (bytes + 255) & ~(size_t)255; return p; };
    int*   startA  = (int*)carve((size_t)(H_HERBS + 1) * sizeof(int));
    int*   startB  = (int*)carve((size_t)(H_HERBS + 1) * sizeof(int));
    float* mpartA  = (float*)carve((size_t)H_HERBS * 64 * sizeof(float));
    float* mpartB  = (float*)carve((size_t)H_HERBS * 64 * sizeof(float));
    float* scoresA = (float*)carve((size_t)nA * sizeof(float));
    float* scoresB = (float*)carve((size_t)nB * sizeof(float));

    int gridA = (nA + 255) / 256;
    int gridB = (nB + 255) / 256;

    k_starts<<<(H_HERBS + 1 + 255) / 256, 256, 0, stream>>>(idxA, idxB, nA, nB, startA, startB);

    k_mean_both<<<2 * H_HERBS, 64, 0, stream>>>(hA, hB, startA, startB, aw1, ab1, mpartA, mpartB);

    k_scores_both<<<gridA + gridB, 256, 0, stream>>>(hA, idxA, mpartA, nA, gridA,
                                                     hB, idxB, mpartB, nB,
                                                     aw1, aw2, ab2, scoresA, scoresB);

    k_attn_both<<<2 * H_HERBS, 64, 0, stream>>>(hA, hB, startA, startB, scoresA, scoresB, outA, outB);

    k_fusion<<<(H_HERBS + HPB - 1) / HPB, 256, 0, stream>>>(outA, outB, fw1, fb1, fw2, fb2, outI);
}